// Round 2
// baseline (383.109 us; speedup 1.0000x reference)
//
#include <hip/hip_runtime.h>
#include <hip/hip_bf16.h>
#include <cstdint>

typedef __attribute__((ext_vector_type(8))) short short8;
typedef __attribute__((ext_vector_type(4))) float f32x4;

#define DEV static __device__ __forceinline__

DEV f32x4 mfma16(short8 a, short8 b, f32x4 c) {
    return __builtin_amdgcn_mfma_f32_16x16x32_bf16(a, b, c, 0, 0, 0);
}

DEV unsigned short f2bf(float f) {
    __hip_bfloat16 h = __float2bfloat16(f);
    return __builtin_bit_cast(unsigned short, h);
}

// global -> LDS direct load, 16B per lane. Dest: wave-uniform base + lane*16.
#define GLOAD16(gp, lp)                                                        \
    __builtin_amdgcn_global_load_lds(                                          \
        (const __attribute__((address_space(1))) unsigned int*)(uintptr_t)(gp),\
        (__attribute__((address_space(3))) unsigned int*)(uintptr_t)(lp),      \
        16, 0, 0)

// ---------------- prep kernels ----------------

__global__ void pe_kernel(float* __restrict__ pe) {
    int i = threadIdx.x;
    if (i >= 512) return;
    float div = expf((float)(2 * i) * (-9.210340371976184f / 1024.0f));
    pe[2 * i]          = 0.0f;      // sin(0*div)
    pe[2 * i + 1]      = 1.0f;      // cos(0*div)
    pe[1024 + 2 * i]     = sinf(div);
    pe[1024 + 2 * i + 1] = cosf(div);
}

__global__ void cvt_bf16(const float* __restrict__ src, unsigned short* __restrict__ dst, int n4) {
    int stride = gridDim.x * blockDim.x;
    for (int i = blockIdx.x * blockDim.x + threadIdx.x; i < n4; i += stride) {
        float4 v = ((const float4*)src)[i];
        ushort4 o;
        o.x = f2bf(v.x); o.y = f2bf(v.y); o.z = f2bf(v.z); o.w = f2bf(v.w);
        ((ushort4*)dst)[i] = o;
    }
}

// mask [2048,2048] int32 (0/1) -> bit-words [2048][64]
__global__ void pack_mask(const int* __restrict__ mask, unsigned int* __restrict__ words) {
    int w = blockIdx.x * blockDim.x + threadIdx.x;   // 0..131071
    const int4* m4 = (const int4*)mask + (size_t)w * 8;
    unsigned int bits = 0;
#pragma unroll
    for (int j = 0; j < 8; j++) {
        int4 v = m4[j];
        bits |= (unsigned)(v.x & 1) << (4 * j);
        bits |= (unsigned)(v.y & 1) << (4 * j + 1);
        bits |= (unsigned)(v.z & 1) << (4 * j + 2);
        bits |= (unsigned)(v.w & 1) << (4 * j + 3);
    }
    words[w] = bits;
}

// ---------------- GEMM mainloop (128x128 tile, BK=32, 4 waves 2x2, K=1024) ----------------
// A: [M,1024] bf16 row-major; Bm: [N,1024] bf16 row-major (B^T form).
DEV void gemm_mainloop(const unsigned short* __restrict__ A,
                       const unsigned short* __restrict__ Bm,
                       int m0, int n0, f32x4 (&acc)[4][4],
                       unsigned short* As, unsigned short* Bs) {
    const int t = threadIdx.x;
    const int w = t >> 6;
    const int l = t & 63, lr = l & 15, lg = l >> 4;
    const int wr = w >> 1, wc = w & 1;
    const int srow = t >> 2;            // staging row 0..63
    const int scol = (t & 3) * 8;       // staging col (elements)
#pragma unroll
    for (int i = 0; i < 4; i++)
#pragma unroll
        for (int j = 0; j < 4; j++) acc[i][j] = f32x4{0.f, 0.f, 0.f, 0.f};

    const unsigned short* Ap = A + (size_t)(m0 + srow) * 1024 + scol;
    const unsigned short* Bp = Bm + (size_t)(n0 + srow) * 1024 + scol;
    unsigned short* dA = As + w * 512;  // wave-uniform LDS dest
    unsigned short* dB = Bs + w * 512;

    for (int k0 = 0; k0 < 1024; k0 += 32) {
        GLOAD16(Ap + k0, dA);
        GLOAD16(Ap + 64 * 1024 + k0, dA + 2048);
        GLOAD16(Bp + k0, dB);
        GLOAD16(Bp + 64 * 1024 + k0, dB + 2048);
        __syncthreads();   // drains vmcnt: LDS tiles ready
        short8 af[4], bfr[4];
#pragma unroll
        for (int i = 0; i < 4; i++)
            af[i] = *(const short8*)(As + (wr * 64 + i * 16 + lr) * 32 + lg * 8);
#pragma unroll
        for (int j = 0; j < 4; j++)
            bfr[j] = *(const short8*)(Bs + (wc * 64 + j * 16 + lr) * 32 + lg * 8);
#pragma unroll
        for (int i = 0; i < 4; i++)
#pragma unroll
            for (int j = 0; j < 4; j++)
                acc[i][j] = mfma16(af[i], bfr[j], acc[i][j]);
        __syncthreads();   // reads done before next stage overwrites
    }
}

// qkv GEMM: M=4096 (b*2048+s), N=3072. Epilogue: +bias, +pe (q,k),
// q *= 1/8 * log2(e) (folds softmax scale AND exp2 conversion),
// scatter q,k -> [B,H,S,64] bf16; v -> vt [B,H,64,S] bf16.
__global__ __launch_bounds__(256) void qkv_gemm(
    const unsigned short* __restrict__ x, const unsigned short* __restrict__ wq,
    const float* __restrict__ bias, const float* __restrict__ pe,
    unsigned short* __restrict__ qo, unsigned short* __restrict__ ko,
    unsigned short* __restrict__ vt) {
    __shared__ unsigned short As[128 * 32], Bs[128 * 32];
    const int m0 = blockIdx.y * 128, n0 = blockIdx.x * 128;
    f32x4 acc[4][4];
    gemm_mainloop(x, wq, m0, n0, acc, As, Bs);

    const int t = threadIdx.x, w = t >> 6, l = t & 63;
    const int wr = w >> 1, wc = w & 1, lr = l & 15, lg = l >> 4;
#pragma unroll
    for (int i = 0; i < 4; i++) {
#pragma unroll
        for (int j = 0; j < 4; j++) {
            const int n = n0 + wc * 64 + j * 16 + lr;
            const int part = n >> 10, d = n & 1023, h = d >> 6, hd = d & 63;
            const float bia = bias[n];
#pragma unroll
            for (int r = 0; r < 4; r++) {
                const int m = m0 + wr * 64 + i * 16 + lg * 4 + r;
                const int b = m >> 11, s = m & 2047;
                float v = acc[i][j][r] + bia;
                if (part == 0) {
                    v = (v + pe[b * 1024 + d]) * 0.1803368801111204f; // 1/8 * log2(e)
                    qo[((size_t)(b * 16 + h) * 2048 + s) * 64 + hd] = f2bf(v);
                } else if (part == 1) {
                    v += pe[b * 1024 + d];
                    ko[((size_t)(b * 16 + h) * 2048 + s) * 64 + hd] = f2bf(v);
                } else {
                    vt[((size_t)(b * 16 + h) * 64 + hd) * 2048 + s] = f2bf(v);
                }
            }
        }
    }
}

// fc GEMM: M=4096, N=1024, out f32 += fc_b
__global__ __launch_bounds__(256) void fc_gemm(
    const unsigned short* __restrict__ a, const unsigned short* __restrict__ wf,
    const float* __restrict__ bias, float* __restrict__ out) {
    __shared__ unsigned short As[128 * 32], Bs[128 * 32];
    const int m0 = blockIdx.y * 128, n0 = blockIdx.x * 128;
    f32x4 acc[4][4];
    gemm_mainloop(a, wf, m0, n0, acc, As, Bs);

    const int t = threadIdx.x, w = t >> 6, l = t & 63;
    const int wr = w >> 1, wc = w & 1, lr = l & 15, lg = l >> 4;
#pragma unroll
    for (int i = 0; i < 4; i++) {
#pragma unroll
        for (int j = 0; j < 4; j++) {
            const int n = n0 + wc * 64 + j * 16 + lr;
            const float bia = bias[n];
#pragma unroll
            for (int r = 0; r < 4; r++) {
                const int m = m0 + wr * 64 + i * 16 + lg * 4 + r;
                out[(size_t)m * 1024 + n] = acc[i][j][r] + bia;
            }
        }
    }
}

// ---------------- flash attention (swapped-QK, in-lane softmax) ----------------
// grid (128 qblocks, 16 heads, 2 batch), 64 thr = 1 wave, 16 q-rows per wave.
// q pre-scaled by 1/8*log2e, so scores are in log2 domain. KBLK=32.
// Swapped QK^T: mfma(K,Q) -> lane owns q-row (lane&15), 8 in-lane key scores.
__global__ __launch_bounds__(64) void attn(
    const unsigned short* __restrict__ q, const unsigned short* __restrict__ k,
    const unsigned short* __restrict__ vt, const unsigned int* __restrict__ mw,
    unsigned short* __restrict__ ao) {
    __shared__ unsigned int P[16 * 20];    // [16 q-rows][16 key-words + pad 4]
    const int l = threadIdx.x, lr = l & 15, lg = l >> 4;
    const int qb = blockIdx.x, h = blockIdx.y, b = blockIdx.z;
    const int bh = b * 16 + h;
    const int q0 = qb * 16;
    const unsigned short* qbase = q + (size_t)bh * 2048 * 64;
    const unsigned short* kbase = k + (size_t)bh * 2048 * 64;
    const unsigned short* vbase = vt + (size_t)bh * 64 * 2048;

    short8 qa[2];
    qa[0] = *(const short8*)(qbase + (q0 + lr) * 64 + lg * 8);
    qa[1] = *(const short8*)(qbase + (q0 + lr) * 64 + 32 + lg * 8);

    f32x4 O[4];
#pragma unroll
    for (int df = 0; df < 4; df++) O[df] = f32x4{0.f, 0.f, 0.f, 0.f};
    float mrow = -3.0e38f, lrow = 0.f;     // stats for q-row = q0+lr

    for (int kb = 0; kb < 64; kb++) {
        // scores^T: sc[ks][r] = score(q=q0+lr, key=kb*32+ks*16+lg*4+r)
        f32x4 sc[2];
#pragma unroll
        for (int ks = 0; ks < 2; ks++) {
            const unsigned short* kp = kbase + (kb * 32 + ks * 16 + lr) * 64 + lg * 8;
            short8 k0 = *(const short8*)kp;
            short8 k1 = *(const short8*)(kp + 32);
            f32x4 z = f32x4{0.f, 0.f, 0.f, 0.f};
            z = mfma16(k0, qa[0], z);
            z = mfma16(k1, qa[1], z);
            sc[ks] = z;
        }
        // mask: one word per lane; key bit = ks*16 + lg*4 + r
        const unsigned int wd = mw[(q0 + lr) * 64 + kb] >> (lg * 4);
#pragma unroll
        for (int r = 0; r < 4; r++) {
            if ((wd >> r) & 1u)        sc[0][r] = -1e9f;
            if ((wd >> (16 + r)) & 1u) sc[1][r] = -1e9f;
        }
        // row max: in-lane tree of 8, then xor16/xor32 across lane groups
        float mx = fmaxf(fmaxf(fmaxf(sc[0][0], sc[0][1]), fmaxf(sc[0][2], sc[0][3])),
                         fmaxf(fmaxf(sc[1][0], sc[1][1]), fmaxf(sc[1][2], sc[1][3])));
        mx = fmaxf(mx, __shfl_xor(mx, 16));
        mx = fmaxf(mx, __shfl_xor(mx, 32));
        // defer-max: only rescale when max grew by > 8 (in log2 units)
        if (!__all(mx <= mrow + 8.0f)) {
            float mn = fmaxf(mrow, mx);
            float a = exp2f(mrow - mn);
            mrow = mn;
            lrow *= a;
            float a0 = __shfl(a, lg * 4 + 0);
            float a1 = __shfl(a, lg * 4 + 1);
            float a2 = __shfl(a, lg * 4 + 2);
            float a3 = __shfl(a, lg * 4 + 3);
#pragma unroll
            for (int df = 0; df < 4; df++) {
                O[df][0] *= a0; O[df][1] *= a1; O[df][2] *= a2; O[df][3] *= a3;
            }
        }
        // p = 2^(s - m); sum in-lane + 2 shuffles
        float p[8];
#pragma unroll
        for (int ks = 0; ks < 2; ks++)
#pragma unroll
            for (int r = 0; r < 4; r++) p[ks * 4 + r] = exp2f(sc[ks][r] - mrow);
        float rs = ((p[0] + p[1]) + (p[2] + p[3])) + ((p[4] + p[5]) + (p[6] + p[7]));
        rs += __shfl_xor(rs, 16);
        rs += __shfl_xor(rs, 32);
        lrow += rs;
        // pack pairs -> 4 u32 LDS words: P[q=lr][m], m = ks*8 + lg*2 + h
        unsigned int* Pr = P + lr * 20;
        Pr[lg * 2 + 0]     = (unsigned)f2bf(p[0]) | ((unsigned)f2bf(p[1]) << 16);
        Pr[lg * 2 + 1]     = (unsigned)f2bf(p[2]) | ((unsigned)f2bf(p[3]) << 16);
        Pr[8 + lg * 2 + 0] = (unsigned)f2bf(p[4]) | ((unsigned)f2bf(p[5]) << 16);
        Pr[8 + lg * 2 + 1] = (unsigned)f2bf(p[6]) | ((unsigned)f2bf(p[7]) << 16);
        // read back as A-fragment: row = lr (q), k-words lg*4..lg*4+3
        short8 pa = *(const short8*)((const unsigned short*)P + lr * 40 + lg * 8);
        // PV: O[q=lg*4+r][d=df*16+lr] += P * V  (V rows from vt = B^T form)
#pragma unroll
        for (int df = 0; df < 4; df++) {
            short8 vf = *(const short8*)(vbase + (df * 16 + lr) * 2048 + kb * 32 + lg * 8);
            O[df] = mfma16(pa, vf, O[df]);
        }
    }
    // finalize: O row q = lg*4+r needs 1/lrow from lane lg*4+r
    float inv = 1.0f / lrow;
    float i0 = __shfl(inv, lg * 4 + 0);
    float i1 = __shfl(inv, lg * 4 + 1);
    float i2 = __shfl(inv, lg * 4 + 2);
    float i3 = __shfl(inv, lg * 4 + 3);
#pragma unroll
    for (int df = 0; df < 4; df++) {
        O[df][0] *= i0; O[df][1] *= i1; O[df][2] *= i2; O[df][3] *= i3;
#pragma unroll
        for (int r = 0; r < 4; r++) {
            int s = q0 + lg * 4 + r;
            int col = h * 64 + df * 16 + lr;
            ao[((size_t)(b * 2048 + s)) * 1024 + col] = f2bf(O[df][r]);
        }
    }
}

// ---------------- launcher ----------------
extern "C" void kernel_launch(void* const* d_in, const int* in_sizes, int n_in,
                              void* d_out, int out_size, void* d_ws, size_t ws_size,
                              hipStream_t stream) {
    const float* x     = (const float*)d_in[0];
    const int*   mask  = (const int*)d_in[1];
    const float* qkv_w = (const float*)d_in[2];
    const float* qkv_b = (const float*)d_in[3];
    const float* fc_w  = (const float*)d_in[4];
    const float* fc_b  = (const float*)d_in[5];
    float* out = (float*)d_out;

    char* ws = (char*)d_ws;
    size_t off = 0;
    auto alloc = [&](size_t bytes) {
        off = (off + 255) & ~(size_t)255;
        void* p = ws + off;
        off += bytes;
        return p;
    };
    float*          pe     = (float*)alloc(2 * 1024 * 4);
    unsigned int*   mwords = (unsigned int*)alloc((size_t)2048 * 64 * 4);
    unsigned short* xb     = (unsigned short*)alloc((size_t)4096 * 1024 * 2);
    unsigned short* wqkv   = (unsigned short*)alloc((size_t)3072 * 1024 * 2);
    unsigned short* wfc    = (unsigned short*)alloc((size_t)1024 * 1024 * 2);
    unsigned short* qb16   = (unsigned short*)alloc((size_t)2 * 16 * 2048 * 64 * 2);
    unsigned short* kb16   = (unsigned short*)alloc((size_t)2 * 16 * 2048 * 64 * 2);
    unsigned short* vtb    = (unsigned short*)alloc((size_t)2 * 16 * 64 * 2048 * 2);
    unsigned short* attn_o = (unsigned short*)alloc((size_t)4096 * 1024 * 2);

    pe_kernel<<<1, 512, 0, stream>>>(pe);
    cvt_bf16<<<1024, 256, 0, stream>>>(x, xb, 4096 * 1024 / 4);
    cvt_bf16<<<768, 256, 0, stream>>>(qkv_w, wqkv, 3072 * 1024 / 4);
    cvt_bf16<<<256, 256, 0, stream>>>(fc_w, wfc, 1024 * 1024 / 4);
    pack_mask<<<512, 256, 0, stream>>>(mask, mwords);
    qkv_gemm<<<dim3(24, 32), 256, 0, stream>>>(xb, wqkv, qkv_b, pe, qb16, kb16, vtb);
    attn<<<dim3(128, 16, 2), 64, 0, stream>>>(qb16, kb16, vtb, mwords, attn_o);
    fc_gemm<<<dim3(8, 32), 256, 0, stream>>>(attn_o, wfc, fc_b, out);
}

// Round 3
// 260.335 us; speedup vs baseline: 1.4716x; 1.4716x over previous
//
#include <hip/hip_runtime.h>
#include <hip/hip_bf16.h>
#include <cstdint>

typedef __attribute__((ext_vector_type(8))) short short8;
typedef __attribute__((ext_vector_type(4))) float f32x4;
typedef __attribute__((ext_vector_type(16))) float f32x16;
typedef __attribute__((ext_vector_type(4))) unsigned uint4v;

#define DEV static __device__ __forceinline__

DEV f32x4 mfma16(short8 a, short8 b, f32x4 c) {
    return __builtin_amdgcn_mfma_f32_16x16x32_bf16(a, b, c, 0, 0, 0);
}
DEV f32x16 mfma32(short8 a, short8 b, f32x16 c) {
    return __builtin_amdgcn_mfma_f32_32x32x16_bf16(a, b, c, 0, 0, 0);
}

DEV unsigned short f2bf(float f) {
    __hip_bfloat16 h = __float2bfloat16(f);
    return __builtin_bit_cast(unsigned short, h);
}

// pack two f32 -> two bf16 in a u32 (lo = first arg), RNE
DEV unsigned cvtpk(float lo, float hi) {
    unsigned r;
    asm("v_cvt_pk_bf16_f32 %0, %1, %2" : "=v"(r) : "v"(lo), "v"(hi));
    return r;
}
// vdst_hi <-> vsrc_lo swap: after, a = {a_lo, b_lo}, b = {a_hi, b_hi}
DEV void plswap(unsigned& a, unsigned& b) {
    asm volatile("v_permlane32_swap_b32 %0, %1" : "+v"(a), "+v"(b));
}

// global -> LDS direct load, 16B per lane. Dest: wave-uniform base + lane*16.
#define GLOAD16(gp, lp)                                                        \
    __builtin_amdgcn_global_load_lds(                                          \
        (const __attribute__((address_space(1))) unsigned int*)(uintptr_t)(gp),\
        (__attribute__((address_space(3))) unsigned int*)(uintptr_t)(lp),      \
        16, 0, 0)

// ---------------- prep kernels ----------------

__global__ void pe_kernel(float* __restrict__ pe) {
    int i = threadIdx.x;
    if (i >= 512) return;
    float div = expf((float)(2 * i) * (-9.210340371976184f / 1024.0f));
    pe[2 * i]          = 0.0f;      // sin(0*div)
    pe[2 * i + 1]      = 1.0f;      // cos(0*div)
    pe[1024 + 2 * i]     = sinf(div);
    pe[1024 + 2 * i + 1] = cosf(div);
}

__global__ void cvt_bf16(const float* __restrict__ src, unsigned short* __restrict__ dst, int n4) {
    int stride = gridDim.x * blockDim.x;
    for (int i = blockIdx.x * blockDim.x + threadIdx.x; i < n4; i += stride) {
        float4 v = ((const float4*)src)[i];
        ushort4 o;
        o.x = f2bf(v.x); o.y = f2bf(v.y); o.z = f2bf(v.z); o.w = f2bf(v.w);
        ((ushort4*)dst)[i] = o;
    }
}

// mask [2048,2048] int32 (0/1) -> bit-words [2048][64]
__global__ void pack_mask(const int* __restrict__ mask, unsigned int* __restrict__ words) {
    int w = blockIdx.x * blockDim.x + threadIdx.x;   // 0..131071
    const int4* m4 = (const int4*)mask + (size_t)w * 8;
    unsigned int bits = 0;
#pragma unroll
    for (int j = 0; j < 8; j++) {
        int4 v = m4[j];
        bits |= (unsigned)(v.x & 1) << (4 * j);
        bits |= (unsigned)(v.y & 1) << (4 * j + 1);
        bits |= (unsigned)(v.z & 1) << (4 * j + 2);
        bits |= (unsigned)(v.w & 1) << (4 * j + 3);
    }
    words[w] = bits;
}

// ---------------- GEMM mainloop (128x128 tile, BK=32, 4 waves 2x2, K=1024) ----------------
DEV void gemm_mainloop(const unsigned short* __restrict__ A,
                       const unsigned short* __restrict__ Bm,
                       int m0, int n0, f32x4 (&acc)[4][4],
                       unsigned short* As, unsigned short* Bs) {
    const int t = threadIdx.x;
    const int w = t >> 6;
    const int l = t & 63, lr = l & 15, lg = l >> 4;
    const int wr = w >> 1, wc = w & 1;
    const int srow = t >> 2;
    const int scol = (t & 3) * 8;
#pragma unroll
    for (int i = 0; i < 4; i++)
#pragma unroll
        for (int j = 0; j < 4; j++) acc[i][j] = f32x4{0.f, 0.f, 0.f, 0.f};

    const unsigned short* Ap = A + (size_t)(m0 + srow) * 1024 + scol;
    const unsigned short* Bp = Bm + (size_t)(n0 + srow) * 1024 + scol;
    unsigned short* dA = As + w * 512;
    unsigned short* dB = Bs + w * 512;

    for (int k0 = 0; k0 < 1024; k0 += 32) {
        GLOAD16(Ap + k0, dA);
        GLOAD16(Ap + 64 * 1024 + k0, dA + 2048);
        GLOAD16(Bp + k0, dB);
        GLOAD16(Bp + 64 * 1024 + k0, dB + 2048);
        __syncthreads();
        short8 af[4], bfr[4];
#pragma unroll
        for (int i = 0; i < 4; i++)
            af[i] = *(const short8*)(As + (wr * 64 + i * 16 + lr) * 32 + lg * 8);
#pragma unroll
        for (int j = 0; j < 4; j++)
            bfr[j] = *(const short8*)(Bs + (wc * 64 + j * 16 + lr) * 32 + lg * 8);
#pragma unroll
        for (int i = 0; i < 4; i++)
#pragma unroll
            for (int j = 0; j < 4; j++)
                acc[i][j] = mfma16(af[i], bfr[j], acc[i][j]);
        __syncthreads();
    }
}

// qkv GEMM: epilogue +bias, +pe (q,k), q *= 1/8*log2e; scatter q,k -> [B,H,S,64]; v -> [B,H,64,S]
__global__ __launch_bounds__(256) void qkv_gemm(
    const unsigned short* __restrict__ x, const unsigned short* __restrict__ wq,
    const float* __restrict__ bias, const float* __restrict__ pe,
    unsigned short* __restrict__ qo, unsigned short* __restrict__ ko,
    unsigned short* __restrict__ vt) {
    __shared__ unsigned short As[128 * 32], Bs[128 * 32];
    const int m0 = blockIdx.y * 128, n0 = blockIdx.x * 128;
    f32x4 acc[4][4];
    gemm_mainloop(x, wq, m0, n0, acc, As, Bs);

    const int t = threadIdx.x, w = t >> 6, l = t & 63;
    const int wr = w >> 1, wc = w & 1, lr = l & 15, lg = l >> 4;
#pragma unroll
    for (int i = 0; i < 4; i++) {
#pragma unroll
        for (int j = 0; j < 4; j++) {
            const int n = n0 + wc * 64 + j * 16 + lr;
            const int part = n >> 10, d = n & 1023, h = d >> 6, hd = d & 63;
            const float bia = bias[n];
#pragma unroll
            for (int r = 0; r < 4; r++) {
                const int m = m0 + wr * 64 + i * 16 + lg * 4 + r;
                const int b = m >> 11, s = m & 2047;
                float v = acc[i][j][r] + bia;
                if (part == 0) {
                    v = (v + pe[b * 1024 + d]) * 0.1803368801111204f; // 1/8 * log2(e)
                    qo[((size_t)(b * 16 + h) * 2048 + s) * 64 + hd] = f2bf(v);
                } else if (part == 1) {
                    v += pe[b * 1024 + d];
                    ko[((size_t)(b * 16 + h) * 2048 + s) * 64 + hd] = f2bf(v);
                } else {
                    vt[((size_t)(b * 16 + h) * 64 + hd) * 2048 + s] = f2bf(v);
                }
            }
        }
    }
}

// fc GEMM: M=4096, N=1024, out f32 += fc_b
__global__ __launch_bounds__(256) void fc_gemm(
    const unsigned short* __restrict__ a, const unsigned short* __restrict__ wf,
    const float* __restrict__ bias, float* __restrict__ out) {
    __shared__ unsigned short As[128 * 32], Bs[128 * 32];
    const int m0 = blockIdx.y * 128, n0 = blockIdx.x * 128;
    f32x4 acc[4][4];
    gemm_mainloop(a, wf, m0, n0, acc, As, Bs);

    const int t = threadIdx.x, w = t >> 6, l = t & 63;
    const int wr = w >> 1, wc = w & 1, lr = l & 15, lg = l >> 4;
#pragma unroll
    for (int i = 0; i < 4; i++) {
#pragma unroll
        for (int j = 0; j < 4; j++) {
            const int n = n0 + wc * 64 + j * 16 + lr;
            const float bia = bias[n];
#pragma unroll
            for (int r = 0; r < 4; r++) {
                const int m = m0 + wr * 64 + i * 16 + lg * 4 + r;
                out[(size_t)m * 1024 + n] = acc[i][j][r] + bia;
            }
        }
    }
}

// ---------------- flash attention: 32x32 MFMA, swapped QK, in-register softmax ----------------
// 1 wave (64 thr) per block, 32 q-rows per wave. KBLK=32, mfma_f32_32x32x16_bf16.
// Lane (c = l&31, hi = l>>5). S^T = mfma(K,Q): col c = q, rows = keys via (reg,hi):
// kr = (reg&3) + 8*(reg>>2) + 4*hi. O^T = mfma(V^T, P): col c = q (stats lane-local),
// rows = d via kr. q pre-scaled by 1/8*log2e (scores in log2 domain).
// XCD swizzle: bid&7 = xcd; each xcd owns 4 (b,h) pairs -> K/V fit its L2.
__global__ __launch_bounds__(64) void attn(
    const unsigned short* __restrict__ q, const unsigned short* __restrict__ k,
    const unsigned short* __restrict__ vt, const unsigned int* __restrict__ mw,
    unsigned short* __restrict__ ao) {
    __shared__ unsigned short T[32 * 72];   // O^T -> O transpose buffer
    const int l = threadIdx.x, c = l & 31, hi = l >> 5;
    const int bid = blockIdx.x;
    const int xcd = bid & 7, idx = bid >> 3;
    const int bh = xcd * 4 + (idx & 3);
    const int qb = idx >> 2;
    const int b = bh >> 4, h = bh & 15;
    const int q0 = qb * 32;

    const unsigned short* qbase = q + (size_t)bh * 2048 * 64;
    const unsigned short* kbase = k + (size_t)bh * 2048 * 64;
    const unsigned short* vbase = vt + (size_t)bh * 64 * 2048;

    // Q B-frag: lane holds Q[q0+c][dstep*16 + hi*8 ..+7]
    short8 qf[4];
#pragma unroll
    for (int d = 0; d < 4; d++)
        qf[d] = *(const short8*)(qbase + (q0 + c) * 64 + d * 16 + hi * 8);

    const unsigned short* kp  = kbase + c * 64 + hi * 8;
    const unsigned short* vp0 = vbase + c * 2048 + hi * 8;         // d = c
    const unsigned short* vp1 = vbase + (32 + c) * 2048 + hi * 8;  // d = 32+c
    const unsigned int*   mp  = mw + (q0 + c) * 64;

    // preload tile 0
    short8 kf[4], vf[2][2];
#pragma unroll
    for (int d = 0; d < 4; d++) kf[d] = *(const short8*)(kp + d * 16);
#pragma unroll
    for (int kc = 0; kc < 2; kc++) {
        vf[0][kc] = *(const short8*)(vp0 + kc * 16);
        vf[1][kc] = *(const short8*)(vp1 + kc * 16);
    }
    unsigned int wd = mp[0];

    f32x16 OT0, OT1;
#pragma unroll
    for (int i = 0; i < 16; i++) { OT0[i] = 0.f; OT1[i] = 0.f; }
    float mrow = -3.0e38f, lrow = 0.f;

#pragma unroll 2
    for (int kb = 0; kb < 64; kb++) {
        // QK^T (K already in regs from prefetch)
        f32x16 S;
#pragma unroll
        for (int i = 0; i < 16; i++) S[i] = 0.f;
#pragma unroll
        for (int d = 0; d < 4; d++) S = mfma32(kf[d], qf[d], S);

        // prefetch tile kb+1 (tail prefetch reads adjacent ws buffers: safe, unused)
        short8 kn[4], vn[2][2];
        const unsigned short* kpn = kp + (kb + 1) * 2048;
#pragma unroll
        for (int d = 0; d < 4; d++) kn[d] = *(const short8*)(kpn + d * 16);
#pragma unroll
        for (int kc = 0; kc < 2; kc++) {
            vn[0][kc] = *(const short8*)(vp0 + (kb + 1) * 32 + kc * 16);
            vn[1][kc] = *(const short8*)(vp1 + (kb + 1) * 32 + kc * 16);
        }
        const unsigned int wn = mp[kb + 1];

        // mask + softmax (all in-lane; q = c for both halves)
        const unsigned int wds = wd >> (4 * hi);
        float p[16];
#pragma unroll
        for (int g = 0; g < 4; g++)
#pragma unroll
            for (int u = 0; u < 4; u++)
                p[g * 4 + u] = (wds & (1u << (8 * g + u))) ? -1e9f : S[g * 4 + u];

        float mx = fmaxf(fmaxf(fmaxf(fmaxf(p[0], p[1]), fmaxf(p[2], p[3])),
                               fmaxf(fmaxf(p[4], p[5]), fmaxf(p[6], p[7]))),
                         fmaxf(fmaxf(fmaxf(p[8], p[9]), fmaxf(p[10], p[11])),
                               fmaxf(fmaxf(p[12], p[13]), fmaxf(p[14], p[15]))));
        mx = fmaxf(mx, __shfl_xor(mx, 32));
        if (!__all(mx <= mrow + 8.0f)) {      // defer-max (T13)
            float mn = fmaxf(mrow, mx);
            float a = exp2f(mrow - mn);
            mrow = mn;
            lrow *= a;
#pragma unroll
            for (int i = 0; i < 16; i++) { OT0[i] *= a; OT1[i] *= a; }
        }
#pragma unroll
        for (int i = 0; i < 16; i++) p[i] = exp2f(p[i] - mrow);
        float rs = (((p[0] + p[1]) + (p[2] + p[3])) + ((p[4] + p[5]) + (p[6] + p[7]))) +
                   (((p[8] + p[9]) + (p[10] + p[11])) + ((p[12] + p[13]) + (p[14] + p[15])));
        rs += __shfl_xor(rs, 32);
        lrow += rs;

        // P -> bf16 A-frag: 8 cvt_pk + 4 permlane32_swap (T12)
        unsigned w8[8];
#pragma unroll
        for (int g = 0; g < 4; g++) {
            w8[2 * g]     = cvtpk(p[4 * g], p[4 * g + 1]);
            w8[2 * g + 1] = cvtpk(p[4 * g + 2], p[4 * g + 3]);
        }
        short8 pa[2];
#pragma unroll
        for (int kc = 0; kc < 2; kc++) {
            unsigned a0 = w8[4 * kc], a2 = w8[4 * kc + 2];
            plswap(a0, a2);                  // a0 = slot0, a2 = slot2
            unsigned a1 = w8[4 * kc + 1], a3 = w8[4 * kc + 3];
            plswap(a1, a3);                  // a1 = slot1, a3 = slot3
            uint4v tv; tv[0] = a0; tv[1] = a1; tv[2] = a2; tv[3] = a3;
            pa[kc] = __builtin_bit_cast(short8, tv);
        }

        // PV: O^T[d][q] += V^T * P
        OT0 = mfma32(vf[0][0], pa[0], OT0);
        OT0 = mfma32(vf[0][1], pa[1], OT0);
        OT1 = mfma32(vf[1][0], pa[0], OT1);
        OT1 = mfma32(vf[1][1], pa[1], OT1);

#pragma unroll
        for (int d = 0; d < 4; d++) kf[d] = kn[d];
#pragma unroll
        for (int kc = 0; kc < 2; kc++) { vf[0][kc] = vn[0][kc]; vf[1][kc] = vn[1][kc]; }
        wd = wn;
    }

    // normalize (lane-local) and transpose O^T -> O via LDS, coalesced store
    float inv = 1.0f / lrow;
#pragma unroll
    for (int i = 0; i < 16; i++) { OT0[i] *= inv; OT1[i] *= inv; }
    unsigned short* Tw = T + c * 72;
#pragma unroll
    for (int g = 0; g < 4; g++)
#pragma unroll
        for (int up = 0; up < 2; up++) {
            const int d0 = 8 * g + 4 * hi + 2 * up;     // even
            *(unsigned*)(Tw + d0)      = cvtpk(OT0[4 * g + 2 * up], OT0[4 * g + 2 * up + 1]);
            *(unsigned*)(Tw + 32 + d0) = cvtpk(OT1[4 * g + 2 * up], OT1[4 * g + 2 * up + 1]);
        }
    __syncthreads();
    const int rq = l >> 1, dh = (l & 1) * 32;
    const unsigned short* Tr = T + rq * 72 + dh;
    unsigned short* gout = ao + ((size_t)(b * 2048 + q0 + rq)) * 1024 + h * 64 + dh;
#pragma unroll
    for (int ch = 0; ch < 4; ch++)
        *(short8*)(gout + ch * 8) = *(const short8*)(Tr + ch * 8);
}

// ---------------- launcher ----------------
extern "C" void kernel_launch(void* const* d_in, const int* in_sizes, int n_in,
                              void* d_out, int out_size, void* d_ws, size_t ws_size,
                              hipStream_t stream) {
    const float* x     = (const float*)d_in[0];
    const int*   mask  = (const int*)d_in[1];
    const float* qkv_w = (const float*)d_in[2];
    const float* qkv_b = (const float*)d_in[3];
    const float* fc_w  = (const float*)d_in[4];
    const float* fc_b  = (const float*)d_in[5];
    float* out = (float*)d_out;

    char* ws = (char*)d_ws;
    size_t off = 0;
    auto alloc = [&](size_t bytes) {
        off = (off + 255) & ~(size_t)255;
        void* p = ws + off;
        off += bytes;
        return p;
    };
    float*          pe     = (float*)alloc(2 * 1024 * 4);
    unsigned int*   mwords = (unsigned int*)alloc((size_t)2048 * 64 * 4);
    unsigned short* xb     = (unsigned short*)alloc((size_t)4096 * 1024 * 2);
    unsigned short* wqkv   = (unsigned short*)alloc((size_t)3072 * 1024 * 2);
    unsigned short* wfc    = (unsigned short*)alloc((size_t)1024 * 1024 * 2);
    unsigned short* qb16   = (unsigned short*)alloc((size_t)2 * 16 * 2048 * 64 * 2);
    unsigned short* kb16   = (unsigned short*)alloc((size_t)2 * 16 * 2048 * 64 * 2);
    unsigned short* vtb    = (unsigned short*)alloc((size_t)2 * 16 * 64 * 2048 * 2);
    unsigned short* attn_o = (unsigned short*)alloc((size_t)4096 * 1024 * 2);

    pe_kernel<<<1, 512, 0, stream>>>(pe);
    cvt_bf16<<<1024, 256, 0, stream>>>(x, xb, 4096 * 1024 / 4);
    cvt_bf16<<<768, 256, 0, stream>>>(qkv_w, wqkv, 3072 * 1024 / 4);
    cvt_bf16<<<256, 256, 0, stream>>>(fc_w, wfc, 1024 * 1024 / 4);
    pack_mask<<<512, 256, 0, stream>>>(mask, mwords);
    qkv_gemm<<<dim3(24, 32), 256, 0, stream>>>(xb, wqkv, qkv_b, pe, qb16, kb16, vtb);
    attn<<<dim3(2048), 64, 0, stream>>>(qb16, kb16, vtb, mwords, attn_o);
    fc_gemm<<<dim3(8, 32), 256, 0, stream>>>(attn_o, wfc, fc_b, out);
}